// Round 8
// baseline (6089.820 us; speedup 1.0000x reference)
//
#include <hip/hip_runtime.h>

typedef unsigned short u16;
typedef unsigned int   u32;
typedef unsigned long long u64;
typedef __attribute__((ext_vector_type(8))) short  bf16x8;
typedef __attribute__((ext_vector_type(4))) float  f32x4;
typedef __attribute__((ext_vector_type(4))) u32    u32x4;

#define B_   128
#define T_   1024
#define I_   64
#define H_   512

#define NG_   8     // batch groups
#define BGRP_ 16    // batch rows per group
#define NBH_  16    // h-chunk blocks per group per layer
#define HC_   32    // h columns per chunk block
#define GCP_  131   // lds_g row stride
#define R_    8     // ring depth (power of 2)
#define L2TRIES 64  // bounded fast-path retries before demotion

__device__ __forceinline__ u16  f2b(float f){ u32 u = __float_as_uint(f); return (u16)((u + 0x7fffu + ((u>>16)&1u))>>16); }
__device__ __forceinline__ float sigf(float x){ return 1.f/(1.f + __expf(-x)); }
__device__ __forceinline__ float tanh_f(float x){
    float a = fabsf(x); float e = __expf(-2.f*a);
    float r = (1.f-e)/(1.f+e); return x<0.f ? -r : r;
}
__device__ __forceinline__ int swz(int row, int colbyte){ return row*1024 + (colbyte ^ ((row&7)<<4)); }

__device__ __forceinline__ bf16x8 ld8f(const float* p){
    float4 a = *(const float4*)p, b = *(const float4*)(p+4);
    bf16x8 r;
    r[0]=(short)f2b(a.x); r[1]=(short)f2b(a.y); r[2]=(short)f2b(a.z); r[3]=(short)f2b(a.w);
    r[4]=(short)f2b(b.x); r[5]=(short)f2b(b.y); r[6]=(short)f2b(b.z); r[7]=(short)f2b(b.w);
    return r;
}

#define MFMA(a,b,c) __builtin_amdgcn_mfma_f32_16x16x32_bf16((a),(b),(c),0,0,0)
#define ALD(p)   __hip_atomic_load((p),  __ATOMIC_RELAXED, __HIP_MEMORY_SCOPE_AGENT)
#define AST(p,v) __hip_atomic_store((p),(v),__ATOMIC_RELAXED, __HIP_MEMORY_SCOPE_AGENT)

// 4 batched L2-coherent (sc0: bypass L1, coherent at XCD L2) dwordx4 loads; wait embedded.
__device__ __forceinline__ void ld4x4_sc0(const u32* p0,const u32* p1,const u32* p2,const u32* p3,
                                          u32x4& a,u32x4& b,u32x4& c,u32x4& d){
    asm volatile("global_load_dwordx4 %0, %4, off sc0\n\t"
                 "global_load_dwordx4 %1, %5, off sc0\n\t"
                 "global_load_dwordx4 %2, %6, off sc0\n\t"
                 "global_load_dwordx4 %3, %7, off sc0\n\t"
                 "s_waitcnt vmcnt(0)"
                 : "=&v"(a),"=&v"(b),"=&v"(c),"=&v"(d)
                 : "v"(p0),"v"(p1),"v"(p2),"v"(p3));
}
// dual store: sc0 (XCD L2 fast path) + agent (MALL safety copy). Same tagged value,
// monotone tags -> every interleaving/eviction benign.
__device__ __forceinline__ void st_h2(u32* p, u32 w0, u32 w1, int l2p){
    if (l2p) {
        u64 pk = (u64)w0 | ((u64)w1<<32);
        asm volatile("global_store_dwordx2 %0, %1, off sc0" :: "v"(p), "v"(pk));
    }
    AST(p, w0); AST(p+1, w1);
}
__device__ __forceinline__ void st_flag(u32* p, u32 v, int l2p){
    if (l2p) asm volatile("global_store_dword %0, %1, off sc0" :: "v"(p), "v"(v));
    AST(p, v);
}

// bounded L2-path staging attempt: returns 1 on success, 0 on budget exhaustion
__device__ __forceinline__ int try_stage_l2(const u32* src, int srow, int jj, u32 tagv, char* lds)
{
    #pragma unroll
    for (int h=0; h<2; ++h) {
        const u32* P0 = src + 4*(16*(4*h+0) + jj);
        const u32* P1 = src + 4*(16*(4*h+1) + jj);
        const u32* P2 = src + 4*(16*(4*h+2) + jj);
        const u32* P3 = src + 4*(16*(4*h+3) + jj);
        u32x4 a,b,c,d;
        int tries = 0;
        for (;;) {
            ld4x4_sc0(P0,P1,P2,P3, a,b,c,d);
            int ok = (int)((a.x>>16)==tagv) & (int)((a.y>>16)==tagv) & (int)((a.z>>16)==tagv) & (int)((a.w>>16)==tagv)
                   & (int)((b.x>>16)==tagv) & (int)((b.y>>16)==tagv) & (int)((b.z>>16)==tagv) & (int)((b.w>>16)==tagv)
                   & (int)((c.x>>16)==tagv) & (int)((c.y>>16)==tagv) & (int)((c.z>>16)==tagv) & (int)((c.w>>16)==tagv)
                   & (int)((d.x>>16)==tagv) & (int)((d.y>>16)==tagv) & (int)((d.z>>16)==tagv) & (int)((d.w>>16)==tagv);
            if (ok) break;
            if (++tries > L2TRIES) return 0;
            __builtin_amdgcn_s_sleep(1);
        }
        u32x4 q[4] = {a,b,c,d};
        #pragma unroll
        for (int i=0;i<4;++i){
            int k = 16*(4*h+i) + jj;
            u32 w0 = (q[i].x&0xffffu) | (q[i].y<<16);
            u32 w1 = (q[i].z&0xffffu) | (q[i].w<<16);
            u64 pk = (u64)w0 | ((u64)w1<<32);
            *(u64*)(lds + swz(srow, 8*k)) = pk;
        }
    }
    return 1;
}

// validate+stage one tagged ring row (512 u32) into swizzled LDS row.
// Fast L2 path with bounded retries; one-way demotion to proven MALL path.
__device__ __forceinline__ void stage_h(const u32* src, int srow, int jj, u32 tagv,
                                        volatile u32* live, char* lds)
{
    if (*live) {
        if (try_stage_l2(src, srow, jj, tagv, lds)) return;
        *live = 0;   // demote this block permanently
    }
    u32 va[16], vb[16];
    for (;;) {
        #pragma unroll
        for (int i=0;i<16;++i){ int p = 16*i + jj; va[i]=ALD(src+2*p); vb[i]=ALD(src+2*p+1); }
        int ok = 1;
        #pragma unroll
        for (int i=0;i<16;++i)
            ok &= (int)((va[i]>>16)==tagv) & (int)((vb[i]>>16)==tagv);
        if (ok) break;
        __builtin_amdgcn_s_sleep(1);
    }
    #pragma unroll
    for (int i=0;i<16;++i){
        int p = 16*i + jj;
        *(u32*)(lds + swz(srow, p*4)) = (va[i]&0xffffu) | (vb[i]<<16);
    }
}

// control block (u32 idx): [0..127] prog, [128..135] claim, [136] bar, [137] oclaim
#define CTL_PROG   0
#define CTL_CLAIM  128
#define CTL_BAR    136
#define CTL_OCLAIM 137

// ---------------- h_init; tagged ring slot R-1 (tag 0); zero control ----------------
__global__ void k_prep(const float* __restrict__ cond, const float* __restrict__ Wc,
                       const float* __restrict__ bc,   const float* __restrict__ Wi,
                       const float* __restrict__ bi,   u32* h0r, u32* h1r, u32* ctl)
{
    __shared__ float cp[32];
    int b = blockIdx.x, tid = threadIdx.x;
    if (b == 0 && tid < 160) AST(&ctl[tid], 0u);
    if (tid < 32) {
        float s = bc[tid];
        #pragma unroll
        for (int i=0;i<10;++i) s += cond[b*10+i]*Wc[tid*10+i];
        cp[tid] = s;
    }
    __syncthreads();
    float s = bi[tid];
    #pragma unroll
    for (int c=0;c<32;++c) s += cp[c]*Wi[tid*32+c];
    u32 v = (u32)f2b(s);                               // tag 0 in hi16
    AST(&h0r[((size_t)(R_-1)*B_ + b)*H_ + tid], v);
    AST(&h1r[((size_t)(R_-1)*B_ + b)*H_ + tid], v);
}

// ---------------- fused 2-layer pipelined LSTM, tagged-data sync, XCD-local L2 fast path ----------------
__global__ __launch_bounds__(256, 1)
void k_fused(const float* __restrict__ x,
             const float* __restrict__ Wih0f, const float* __restrict__ Whh0f,
             const float* __restrict__ Wih1f, const float* __restrict__ Whh1f,
             const float* __restrict__ bih0f, const float* __restrict__ bhh0f,
             const float* __restrict__ bih1f, const float* __restrict__ bhh1f,
             u32* h0r, u32* h1r, u32* ctl, float* hlast)
{
    __shared__ u16  lds_a[BGRP_*H_];
    __shared__ u16  lds_b[BGRP_*H_];
    __shared__ float lds_g[BGRP_*GCP_];
    __shared__ int  sh_role, sh_l2;
    __shared__ u32  sh_live_s;
    volatile u32* live = &sh_live_s;

    const int tid = threadIdx.x;
    const int w = tid>>6, lane = tid&63;

    // ---- self-organization: claim a role on own physical XCD ----
    if (tid == 0) {
        u32 xcc = __builtin_amdgcn_s_getreg(6164) & 7u;   // hwreg(HW_REG_XCC_ID=20,0,4)
        u32 idx = atomicAdd(&ctl[CTL_CLAIM + xcc], 1u);
        int role = (idx < 32u) ? (int)(xcc*32u + idx) : -1;
        atomicAdd(&ctl[CTL_BAR], 1u);
        while (ALD(&ctl[CTL_BAR]) < 256u) __builtin_amdgcn_s_sleep(8);
        if (role < 0) {
            u32 o = atomicAdd(&ctl[CTL_OCLAIM], 1u);
            u32 acc = 0; int g = 0, slot = 0;
            for (g = 0; g < 8; ++g) {
                u32 cnt = ALD(&ctl[CTL_CLAIM + g]); if (cnt > 32u) cnt = 32u;
                u32 left = 32u - cnt;
                if (o < acc + left) { slot = (int)(cnt + (o - acc)); break; }
                acc += left;
            }
            role = g*32 + slot;
        }
        sh_role = role;
        int l2 = (ALD(&ctl[CTL_CLAIM + (role>>5)]) >= 32u) ? 1 : 0;
        sh_l2 = l2;
        sh_live_s = (u32)l2;
    }
    __syncthreads();
    const int role = sh_role;
    const int L2P  = sh_l2;
    const int grp = role>>5, layer = (role>>4)&1, chunk = role&15;
    const int n0 = chunk*HC_;
    const int gb = grp*BGRP_;
    u32* prog = ctl + CTL_PROG + grp*NBH_;

    const int prow = tid>>4;
    const int phc  = (2*tid)&31;
    const int srow = tid>>4, jj = tid&15;

    const float* ba = (layer==0) ? bih0f : bih1f;
    const float* bb = (layer==0) ? bhh0f : bhh1f;
    float bias[8];
    #pragma unroll
    for (int q=0;q<4;++q){
        int idx = q*H_ + n0 + phc;
        bias[2*q]   = ba[idx]   + bb[idx];
        bias[2*q+1] = ba[idx+1] + bb[idx+1];
    }

    float c0 = 0.f, c1 = 0.f;

    const int s0i = 2*w*16 + (lane&15), s1i = s0i+16;
    const int r0 = (s0i>>5)*H_ + n0 + (s0i&31);
    const int r1 = (s1i>>5)*H_ + n0 + (s1i&31);
    const int kc = (lane>>4)*8;

    if (layer == 0) {
        bf16x8 bh0[16], bh1[16], bx0[2], bx1[2];
        {
            const float* p0 = Whh0f + (size_t)r0*H_ + kc;
            const float* p1 = Whh0f + (size_t)r1*H_ + kc;
            #pragma unroll
            for (int kt=0;kt<16;++kt){ bh0[kt]=ld8f(p0+kt*32); bh1[kt]=ld8f(p1+kt*32); }
            const float* q0 = Wih0f + (size_t)r0*I_ + kc;
            const float* q1 = Wih0f + (size_t)r1*I_ + kc;
            #pragma unroll
            for (int kt=0;kt<2;++kt){ bx0[kt]=ld8f(q0+kt*32); bx1[kt]=ld8f(q1+kt*32); }
        }

        for (int t = 0; t < T_; ++t) {
            const float* xp = x + ((size_t)(gb+srow)*T_ + t)*I_ + jj*4;
            float4 xv = *(const float4*)xp;

            // backpressure: L1 staged step t-(R-1); bounded fast path, demote on exhaustion
            if (tid < 16) {
                const int need = t - (R_-1);
                if (need > 0) {
                    int fast = (int)*live;
                    if (fast) {
                        int tries = 0;
                        for (;;) {
                            u32 f;
                            asm volatile("global_load_dword %0, %1, off sc0\n\ts_waitcnt vmcnt(0)"
                                         : "=&v"(f) : "v"(prog + tid));
                            if ((int)f >= need) break;
                            if (++tries > L2TRIES) { *live = 0; fast = 0; break; }
                            __builtin_amdgcn_s_sleep(1);
                        }
                    }
                    if (!fast)
                        while ((int)ALD(&prog[tid]) < need) __builtin_amdgcn_s_sleep(1);
                }
            }

            // stage h0[t-1]: slot (t-1)&7, tag t
            stage_h(h0r + ((size_t)((t + R_ - 1)&(R_-1))*B_ + gb + srow)*H_,
                    srow, jj, (u32)t, live, (char*)lds_a);
            {
                u16 a=f2b(xv.x), b=f2b(xv.y), c=f2b(xv.z), d=f2b(xv.w);
                u64 pk = (u64)((u32)a|((u32)b<<16)) | ((u64)((u32)c|((u32)d<<16))<<32);
                *(u64*)((char*)lds_b + srow*128 + ((jj*8) ^ ((srow&7)<<4))) = pk;
            }
            __syncthreads();   // S2

            f32x4 acc0 = {0.f,0.f,0.f,0.f}, acc1 = {0.f,0.f,0.f,0.f};
            #pragma unroll
            for (int kt=0;kt<2;++kt){
                bf16x8 a = *(const bf16x8*)((char*)lds_b + (lane&15)*128 + ((kt*64 + (lane>>4)*16) ^ ((lane&7)<<4)));
                acc0 = MFMA(a, bx0[kt], acc0);
                acc1 = MFMA(a, bx1[kt], acc1);
            }
            #pragma unroll
            for (int kt=0;kt<16;++kt){
                bf16x8 a = *(const bf16x8*)((char*)lds_a + swz(lane&15, kt*64 + (lane>>4)*16));
                acc0 = MFMA(a, bh0[kt], acc0);
                acc1 = MFMA(a, bh1[kt], acc1);
            }
            {
                int gr=(lane>>4)*4, gc=lane&15;
                #pragma unroll
                for (int j=0;j<4;++j){
                    lds_g[(gr+j)*GCP_ + 2*w*16      + gc] = acc0[j];
                    lds_g[(gr+j)*GCP_ + (2*w+1)*16  + gc] = acc1[j];
                }
            }
            __syncthreads();   // S3

            {
                float2 gi = *(const float2*)&lds_g[prow*GCP_ +      phc];
                float2 gf = *(const float2*)&lds_g[prow*GCP_ + 32 + phc];
                float2 gg = *(const float2*)&lds_g[prow*GCP_ + 64 + phc];
                float2 go = *(const float2*)&lds_g[prow*GCP_ + 96 + phc];
                c0 = sigf(gf.x+bias[2])*c0 + sigf(gi.x+bias[0])*tanh_f(gg.x+bias[4]);
                c1 = sigf(gf.y+bias[3])*c1 + sigf(gi.y+bias[1])*tanh_f(gg.y+bias[5]);
                float h0v = sigf(go.x+bias[6])*tanh_f(c0);
                float h1v = sigf(go.y+bias[7])*tanh_f(c1);
                const u32 tg = (u32)(t+1)<<16;
                u32* dst = h0r + ((size_t)(t&(R_-1))*B_ + gb + prow)*H_ + n0 + phc;
                st_h2(dst, tg | (u32)f2b(h0v), tg | (u32)f2b(h1v), L2P);
            }
        }
    } else {
        bf16x8 bi0[16], bi1[16], bh0[16], bh1[16];
        {
            const float* p0 = Wih1f + (size_t)r0*H_ + kc;
            const float* p1 = Wih1f + (size_t)r1*H_ + kc;
            const float* q0 = Whh1f + (size_t)r0*H_ + kc;
            const float* q1 = Whh1f + (size_t)r1*H_ + kc;
            #pragma unroll
            for (int kt=0;kt<16;++kt){
                bi0[kt]=ld8f(p0+kt*32); bi1[kt]=ld8f(p1+kt*32);
                bh0[kt]=ld8f(q0+kt*32); bh1[kt]=ld8f(q1+kt*32);
            }
        }

        for (int t = 0; t < T_; ++t) {
            // stage h0[t] (slot t&7, tag t+1) ; h1[t-1] (slot (t-1)&7, tag t)
            stage_h(h0r + ((size_t)(t&(R_-1))*B_ + gb + srow)*H_,
                    srow, jj, (u32)(t+1), live, (char*)lds_a);
            stage_h(h1r + ((size_t)((t + R_ - 1)&(R_-1))*B_ + gb + srow)*H_,
                    srow, jj, (u32)t, live, (char*)lds_b);
            __syncthreads();   // S2

            if (tid == 0) st_flag(&prog[chunk], (u32)(t+1), L2P);

            f32x4 acc0 = {0.f,0.f,0.f,0.f}, acc1 = {0.f,0.f,0.f,0.f};
            #pragma unroll
            for (int kt=0;kt<16;++kt){
                bf16x8 a0 = *(const bf16x8*)((char*)lds_a + swz(lane&15, kt*64 + (lane>>4)*16));
                bf16x8 a1 = *(const bf16x8*)((char*)lds_b + swz(lane&15, kt*64 + (lane>>4)*16));
                acc0 = MFMA(a0, bi0[kt], acc0);
                acc1 = MFMA(a0, bi1[kt], acc1);
                acc0 = MFMA(a1, bh0[kt], acc0);
                acc1 = MFMA(a1, bh1[kt], acc1);
            }
            {
                int gr=(lane>>4)*4, gc=lane&15;
                #pragma unroll
                for (int j=0;j<4;++j){
                    lds_g[(gr+j)*GCP_ + 2*w*16      + gc] = acc0[j];
                    lds_g[(gr+j)*GCP_ + (2*w+1)*16  + gc] = acc1[j];
                }
            }
            __syncthreads();   // S3

            {
                float2 gi = *(const float2*)&lds_g[prow*GCP_ +      phc];
                float2 gf = *(const float2*)&lds_g[prow*GCP_ + 32 + phc];
                float2 gg = *(const float2*)&lds_g[prow*GCP_ + 64 + phc];
                float2 go = *(const float2*)&lds_g[prow*GCP_ + 96 + phc];
                c0 = sigf(gf.x+bias[2])*c0 + sigf(gi.x+bias[0])*tanh_f(gg.x+bias[4]);
                c1 = sigf(gf.y+bias[3])*c1 + sigf(gi.y+bias[1])*tanh_f(gg.y+bias[5]);
                float h0v = sigf(go.x+bias[6])*tanh_f(c0);
                float h1v = sigf(go.y+bias[7])*tanh_f(c1);
                const u32 tg = (u32)(t+1)<<16;
                u32* dst = h1r + ((size_t)(t&(R_-1))*B_ + gb + prow)*H_ + n0 + phc;
                st_h2(dst, tg | (u32)f2b(h0v), tg | (u32)f2b(h1v), L2P);
                if (t == T_-1) {
                    hlast[(size_t)(gb+prow)*H_ + n0 + phc    ] = h0v;
                    hlast[(size_t)(gb+prow)*H_ + n0 + phc + 1] = h1v;
                }
            }
        }
    }
}

// ---------------- output head ----------------
__global__ void k_out(const float* __restrict__ hlast, const float* __restrict__ Wout,
                      const float* __restrict__ bout, float* __restrict__ y)
{
    int b = blockIdx.x;
    int w = threadIdx.x>>6, lane = threadIdx.x&63;
    const float* hp = hlast + (size_t)b*H_;
    #pragma unroll
    for (int oo=0; oo<4; ++oo) {
        int o = w*4 + oo;
        const float* wp = Wout + (size_t)o*H_;
        float p = 0.f;
        for (int k=lane; k<H_; k+=64) p += hp[k]*wp[k];
        #pragma unroll
        for (int off=32; off; off>>=1) p += __shfl_down(p, off);
        if (lane==0) y[b*16 + o] = p + bout[o];
    }
}

// ---------------- workspace layout (~4.3MB) ----------------
static constexpr size_t OFF_H0R = 0;
static constexpr size_t OFF_H1R = OFF_H0R + (size_t)R_*B_*H_*4;  // 2MB
static constexpr size_t OFF_HL  = OFF_H1R + (size_t)R_*B_*H_*4;  // 2MB
static constexpr size_t OFF_CTL = OFF_HL  + (size_t)B_*H_*4;     // 256KB

extern "C" void kernel_launch(void* const* d_in, const int* in_sizes, int n_in,
                              void* d_out, int out_size, void* d_ws, size_t ws_size,
                              hipStream_t stream)
{
    (void)in_sizes; (void)n_in; (void)out_size; (void)ws_size;
    const float* x    = (const float*)d_in[0];
    const float* cond = (const float*)d_in[1];
    const float* Wc   = (const float*)d_in[2];
    const float* bc   = (const float*)d_in[3];
    const float* Wi   = (const float*)d_in[4];
    const float* bi   = (const float*)d_in[5];
    const float* Wih0 = (const float*)d_in[6];
    const float* Whh0 = (const float*)d_in[7];
    const float* bih0 = (const float*)d_in[8];
    const float* bhh0 = (const float*)d_in[9];
    const float* Wih1 = (const float*)d_in[10];
    const float* Whh1 = (const float*)d_in[11];
    const float* bih1 = (const float*)d_in[12];
    const float* bhh1 = (const float*)d_in[13];
    const float* Wout = (const float*)d_in[14];
    const float* bout = (const float*)d_in[15];
    float* y = (float*)d_out;
    char* ws = (char*)d_ws;

    u32* h0r  = (u32*)(ws + OFF_H0R);
    u32* h1r  = (u32*)(ws + OFF_H1R);
    float* hl = (float*)(ws + OFF_HL);
    u32* ctl  = (u32*)(ws + OFF_CTL);

    k_prep<<<B_, 512, 0, stream>>>(cond, Wc, bc, Wi, bi, h0r, h1r, ctl);

    k_fused<<<2*NBH_*NG_, 256, 0, stream>>>(x, Wih0, Whh0, Wih1, Whh1,
                                            bih0, bhh0, bih1, bhh1,
                                            h0r, h1r, ctl, hl);

    k_out<<<B_, 256, 0, stream>>>(hl, Wout, bout, y);
}

// Round 9
// 4222.602 us; speedup vs baseline: 1.4422x; 1.4422x over previous
//
#include <hip/hip_runtime.h>

typedef unsigned short u16;
typedef unsigned int   u32;
typedef unsigned long long u64;
typedef __attribute__((ext_vector_type(8))) short  bf16x8;
typedef __attribute__((ext_vector_type(4))) float  f32x4;
typedef __attribute__((ext_vector_type(4))) u32    u32x4;

#define B_   128
#define T_   1024
#define I_   64
#define H_   512

#define NG_   8     // batch groups
#define BGRP_ 16    // batch rows per group
#define NBH_  16    // h-chunk blocks per group per layer
#define HC_   32    // h columns per chunk block
#define GCP_  131   // lds_g row stride
#define R_    8     // ring depth (power of 2)

static constexpr size_t MIRu = (size_t)R_*B_*H_;   // fast->mirror offset in u32 elems (2MB)

__device__ __forceinline__ u16  f2b(float f){ u32 u = __float_as_uint(f); return (u16)((u + 0x7fffu + ((u>>16)&1u))>>16); }
__device__ __forceinline__ float sigf(float x){ return 1.f/(1.f + __expf(-x)); }
__device__ __forceinline__ float tanh_f(float x){
    float a = fabsf(x); float e = __expf(-2.f*a);
    float r = (1.f-e)/(1.f+e); return x<0.f ? -r : r;
}
__device__ __forceinline__ int swz(int row, int colbyte){ return row*1024 + (colbyte ^ ((row&7)<<4)); }

__device__ __forceinline__ bf16x8 ld8f(const float* p){
    float4 a = *(const float4*)p, b = *(const float4*)(p+4);
    bf16x8 r;
    r[0]=(short)f2b(a.x); r[1]=(short)f2b(a.y); r[2]=(short)f2b(a.z); r[3]=(short)f2b(a.w);
    r[4]=(short)f2b(b.x); r[5]=(short)f2b(b.y); r[6]=(short)f2b(b.z); r[7]=(short)f2b(b.w);
    return r;
}

#define MFMA(a,b,c) __builtin_amdgcn_mfma_f32_16x16x32_bf16((a),(b),(c),0,0,0)
#define ALD(p)   __hip_atomic_load((p),  __ATOMIC_RELAXED, __HIP_MEMORY_SCOPE_AGENT)
#define AST(p,v) __hip_atomic_store((p),(v),__ATOMIC_RELAXED, __HIP_MEMORY_SCOPE_AGENT)

// 4 batched L2-coherent loads (sc0: bypass L1, served by XCD L2)
__device__ __forceinline__ void ld4x4_sc0(const u32* p0,const u32* p1,const u32* p2,const u32* p3,
                                          u32x4& a,u32x4& b,u32x4& c,u32x4& d){
    asm volatile("global_load_dwordx4 %0, %4, off sc0\n\t"
                 "global_load_dwordx4 %1, %5, off sc0\n\t"
                 "global_load_dwordx4 %2, %6, off sc0\n\t"
                 "global_load_dwordx4 %3, %7, off sc0\n\t"
                 "s_waitcnt vmcnt(0)"
                 : "=&v"(a),"=&v"(b),"=&v"(c),"=&v"(d)
                 : "v"(p0),"v"(p1),"v"(p2),"v"(p3));
}
// 4 batched MALL-coherent loads (sc0+sc1: bypass L1 and L2)
__device__ __forceinline__ void ld4x4_mall(const u32* p0,const u32* p1,const u32* p2,const u32* p3,
                                           u32x4& a,u32x4& b,u32x4& c,u32x4& d){
    asm volatile("global_load_dwordx4 %0, %4, off sc0 sc1\n\t"
                 "global_load_dwordx4 %1, %5, off sc0 sc1\n\t"
                 "global_load_dwordx4 %2, %6, off sc0 sc1\n\t"
                 "global_load_dwordx4 %3, %7, off sc0 sc1\n\t"
                 "s_waitcnt vmcnt(0)"
                 : "=&v"(a),"=&v"(b),"=&v"(c),"=&v"(d)
                 : "v"(p0),"v"(p1),"v"(p2),"v"(p3));
}
// producer store: fast ring (sc0 -> local L2) if l2p, always mirror (sc0 sc1 -> MALL).
// DISJOINT addresses: the mirror store never touches the fast ring's L2 line.
__device__ __forceinline__ void st_h2(u32* p, u32 w0, u32 w1, int l2p){
    u64 pk = (u64)w0 | ((u64)w1<<32);
    if (l2p)
        asm volatile("global_store_dwordx2 %0, %1, off sc0" :: "v"(p), "v"(pk));
    asm volatile("global_store_dwordx2 %0, %1, off sc0 sc1" :: "v"(p + MIRu), "v"(pk));
}

#define QOK(q,tag) ((int)(((q).x>>16)==(tag)) & (int)(((q).y>>16)==(tag)) \
                  & (int)(((q).z>>16)==(tag)) & (int)(((q).w>>16)==(tag)))

// validate+stage one tagged ring row (512 u32) into swizzled LDS row.
// l2p: interleave fast(L2) and mirror(MALL) polls, accept whichever validates.
// Termination unconditional: mirror path is the proven round-6 protocol.
__device__ __forceinline__ void stage_h(const u32* fsrc, int srow, int jj, u32 tagv,
                                        int l2p, char* lds)
{
    #pragma unroll
    for (int h=0; h<2; ++h) {
        const u32* F0 = fsrc + 4*(16*(4*h+0) + jj);
        const u32* F1 = fsrc + 4*(16*(4*h+1) + jj);
        const u32* F2 = fsrc + 4*(16*(4*h+2) + jj);
        const u32* F3 = fsrc + 4*(16*(4*h+3) + jj);
        u32x4 a,b,c,d;
        if (l2p) {
            for (;;) {
                ld4x4_sc0(F0,F1,F2,F3, a,b,c,d);
                if (QOK(a,tagv)&QOK(b,tagv)&QOK(c,tagv)&QOK(d,tagv)) break;
                ld4x4_mall(F0+MIRu,F1+MIRu,F2+MIRu,F3+MIRu, a,b,c,d);
                if (QOK(a,tagv)&QOK(b,tagv)&QOK(c,tagv)&QOK(d,tagv)) break;
                __builtin_amdgcn_s_sleep(1);
            }
        } else {
            for (;;) {
                ld4x4_mall(F0+MIRu,F1+MIRu,F2+MIRu,F3+MIRu, a,b,c,d);
                if (QOK(a,tagv)&QOK(b,tagv)&QOK(c,tagv)&QOK(d,tagv)) break;
                __builtin_amdgcn_s_sleep(1);
            }
        }
        u32x4 q[4] = {a,b,c,d};
        #pragma unroll
        for (int i=0;i<4;++i){
            int k = 16*(4*h+i) + jj;
            u32 w0 = (q[i].x&0xffffu) | (q[i].y<<16);
            u32 w1 = (q[i].z&0xffffu) | (q[i].w<<16);
            u64 pk = (u64)w0 | ((u64)w1<<32);
            *(u64*)(lds + swz(srow, 8*k)) = pk;
        }
    }
}

// control block (u32 idx): [0..127] prog, [128..135] claim, [136] bar, [137] oclaim
#define CTL_PROG   0
#define CTL_CLAIM  128
#define CTL_BAR    136
#define CTL_OCLAIM 137

// ---------------- h_init; tagged ring slot R-1 (tag 0) in fast+mirror; zero control ----------------
__global__ void k_prep(const float* __restrict__ cond, const float* __restrict__ Wc,
                       const float* __restrict__ bc,   const float* __restrict__ Wi,
                       const float* __restrict__ bi,   u32* h0f, u32* h1f, u32* ctl)
{
    __shared__ float cp[32];
    int b = blockIdx.x, tid = threadIdx.x;
    if (b == 0 && tid < 160) AST(&ctl[tid], 0u);
    if (tid < 32) {
        float s = bc[tid];
        #pragma unroll
        for (int i=0;i<10;++i) s += cond[b*10+i]*Wc[tid*10+i];
        cp[tid] = s;
    }
    __syncthreads();
    float s = bi[tid];
    #pragma unroll
    for (int c=0;c<32;++c) s += cp[c]*Wi[tid*32+c];
    u32 v = (u32)f2b(s);                               // tag 0 in hi16
    size_t off = ((size_t)(R_-1)*B_ + b)*H_ + tid;
    AST(&h0f[off], v);  AST(&h0f[off + MIRu], v);
    AST(&h1f[off], v);  AST(&h1f[off + MIRu], v);
}

// ---------------- fused 2-layer pipelined LSTM, tagged-data sync, L2 fast path + MALL mirror ----------------
__global__ __launch_bounds__(256, 1)
void k_fused(const float* __restrict__ x,
             const float* __restrict__ Wih0f, const float* __restrict__ Whh0f,
             const float* __restrict__ Wih1f, const float* __restrict__ Whh1f,
             const float* __restrict__ bih0f, const float* __restrict__ bhh0f,
             const float* __restrict__ bih1f, const float* __restrict__ bhh1f,
             u32* h0f, u32* h1f, u32* ctl, float* hlast)
{
    __shared__ u16  lds_a[BGRP_*H_];
    __shared__ u16  lds_b[BGRP_*H_];
    __shared__ float lds_g[BGRP_*GCP_];
    __shared__ int  sh_role, sh_l2;

    const int tid = threadIdx.x;
    const int w = tid>>6, lane = tid&63;

    // ---- self-organization: claim a role on own physical XCD ----
    if (tid == 0) {
        u32 xcc = __builtin_amdgcn_s_getreg(6164) & 7u;   // hwreg(HW_REG_XCC_ID=20,0,4)
        u32 idx = atomicAdd(&ctl[CTL_CLAIM + xcc], 1u);
        int role = (idx < 32u) ? (int)(xcc*32u + idx) : -1;
        atomicAdd(&ctl[CTL_BAR], 1u);
        while (ALD(&ctl[CTL_BAR]) < 256u) __builtin_amdgcn_s_sleep(8);
        if (role < 0) {
            u32 o = atomicAdd(&ctl[CTL_OCLAIM], 1u);
            u32 acc = 0; int g = 0, slot = 0;
            for (g = 0; g < 8; ++g) {
                u32 cnt = ALD(&ctl[CTL_CLAIM + g]); if (cnt > 32u) cnt = 32u;
                u32 left = 32u - cnt;
                if (o < acc + left) { slot = (int)(cnt + (o - acc)); break; }
                acc += left;
            }
            role = g*32 + slot;
        }
        sh_role = role;
        sh_l2 = (ALD(&ctl[CTL_CLAIM + (role>>5)]) >= 32u) ? 1 : 0;
    }
    __syncthreads();
    const int role = sh_role;
    const int L2P  = sh_l2;
    const int grp = role>>5, layer = (role>>4)&1, chunk = role&15;
    const int n0 = chunk*HC_;
    const int gb = grp*BGRP_;
    u32* prog = ctl + CTL_PROG + grp*NBH_;

    const int prow = tid>>4;
    const int phc  = (2*tid)&31;
    const int srow = tid>>4, jj = tid&15;

    const float* ba = (layer==0) ? bih0f : bih1f;
    const float* bb = (layer==0) ? bhh0f : bhh1f;
    float bias[8];
    #pragma unroll
    for (int q=0;q<4;++q){
        int idx = q*H_ + n0 + phc;
        bias[2*q]   = ba[idx]   + bb[idx];
        bias[2*q+1] = ba[idx+1] + bb[idx+1];
    }

    float c0 = 0.f, c1 = 0.f;

    const int s0i = 2*w*16 + (lane&15), s1i = s0i+16;
    const int r0 = (s0i>>5)*H_ + n0 + (s0i&31);
    const int r1 = (s1i>>5)*H_ + n0 + (s1i&31);
    const int kc = (lane>>4)*8;

    if (layer == 0) {
        bf16x8 bh0[16], bh1[16], bx0[2], bx1[2];
        {
            const float* p0 = Whh0f + (size_t)r0*H_ + kc;
            const float* p1 = Whh0f + (size_t)r1*H_ + kc;
            #pragma unroll
            for (int kt=0;kt<16;++kt){ bh0[kt]=ld8f(p0+kt*32); bh1[kt]=ld8f(p1+kt*32); }
            const float* q0 = Wih0f + (size_t)r0*I_ + kc;
            const float* q1 = Wih0f + (size_t)r1*I_ + kc;
            #pragma unroll
            for (int kt=0;kt<2;++kt){ bx0[kt]=ld8f(q0+kt*32); bx1[kt]=ld8f(q1+kt*32); }
        }

        for (int t = 0; t < T_; ++t) {
            const float* xp = x + ((size_t)(gb+srow)*T_ + t)*I_ + jj*4;
            float4 xv = *(const float4*)xp;

            // backpressure: L1 staged step t-(R-1) (MALL flags; off critical path, R-slack)
            if (tid < 16) {
                const int need = t - (R_-1);
                if (need > 0)
                    while ((int)ALD(&prog[tid]) < need) __builtin_amdgcn_s_sleep(1);
            }

            // stage h0[t-1]: slot (t-1)&7, tag t
            stage_h(h0f + ((size_t)((t + R_ - 1)&(R_-1))*B_ + gb + srow)*H_,
                    srow, jj, (u32)t, L2P, (char*)lds_a);
            {
                u16 a=f2b(xv.x), b=f2b(xv.y), c=f2b(xv.z), d=f2b(xv.w);
                u64 pk = (u64)((u32)a|((u32)b<<16)) | ((u64)((u32)c|((u32)d<<16))<<32);
                *(u64*)((char*)lds_b + srow*128 + ((jj*8) ^ ((srow&7)<<4))) = pk;
            }
            __syncthreads();   // S2

            f32x4 acc0 = {0.f,0.f,0.f,0.f}, acc1 = {0.f,0.f,0.f,0.f};
            #pragma unroll
            for (int kt=0;kt<2;++kt){
                bf16x8 a = *(const bf16x8*)((char*)lds_b + (lane&15)*128 + ((kt*64 + (lane>>4)*16) ^ ((lane&7)<<4)));
                acc0 = MFMA(a, bx0[kt], acc0);
                acc1 = MFMA(a, bx1[kt], acc1);
            }
            #pragma unroll
            for (int kt=0;kt<16;++kt){
                bf16x8 a = *(const bf16x8*)((char*)lds_a + swz(lane&15, kt*64 + (lane>>4)*16));
                acc0 = MFMA(a, bh0[kt], acc0);
                acc1 = MFMA(a, bh1[kt], acc1);
            }
            {
                int gr=(lane>>4)*4, gc=lane&15;
                #pragma unroll
                for (int j=0;j<4;++j){
                    lds_g[(gr+j)*GCP_ + 2*w*16      + gc] = acc0[j];
                    lds_g[(gr+j)*GCP_ + (2*w+1)*16  + gc] = acc1[j];
                }
            }
            __syncthreads();   // S3

            {
                float2 gi = *(const float2*)&lds_g[prow*GCP_ +      phc];
                float2 gf = *(const float2*)&lds_g[prow*GCP_ + 32 + phc];
                float2 gg = *(const float2*)&lds_g[prow*GCP_ + 64 + phc];
                float2 go = *(const float2*)&lds_g[prow*GCP_ + 96 + phc];
                c0 = sigf(gf.x+bias[2])*c0 + sigf(gi.x+bias[0])*tanh_f(gg.x+bias[4]);
                c1 = sigf(gf.y+bias[3])*c1 + sigf(gi.y+bias[1])*tanh_f(gg.y+bias[5]);
                float h0v = sigf(go.x+bias[6])*tanh_f(c0);
                float h1v = sigf(go.y+bias[7])*tanh_f(c1);
                const u32 tg = (u32)(t+1)<<16;
                u32* dst = h0f + ((size_t)(t&(R_-1))*B_ + gb + prow)*H_ + n0 + phc;
                st_h2(dst, tg | (u32)f2b(h0v), tg | (u32)f2b(h1v), L2P);
            }
        }
    } else {
        bf16x8 bi0[16], bi1[16], bh0[16], bh1[16];
        {
            const float* p0 = Wih1f + (size_t)r0*H_ + kc;
            const float* p1 = Wih1f + (size_t)r1*H_ + kc;
            const float* q0 = Whh1f + (size_t)r0*H_ + kc;
            const float* q1 = Whh1f + (size_t)r1*H_ + kc;
            #pragma unroll
            for (int kt=0;kt<16;++kt){
                bi0[kt]=ld8f(p0+kt*32); bi1[kt]=ld8f(p1+kt*32);
                bh0[kt]=ld8f(q0+kt*32); bh1[kt]=ld8f(q1+kt*32);
            }
        }

        for (int t = 0; t < T_; ++t) {
            // stage h0[t] (slot t&7, tag t+1) ; h1[t-1] (slot (t-1)&7, tag t)
            stage_h(h0f + ((size_t)(t&(R_-1))*B_ + gb + srow)*H_,
                    srow, jj, (u32)(t+1), L2P, (char*)lds_a);
            stage_h(h1f + ((size_t)((t + R_ - 1)&(R_-1))*B_ + gb + srow)*H_,
                    srow, jj, (u32)t, L2P, (char*)lds_b);
            __syncthreads();   // S2

            if (tid == 0) AST(&prog[chunk], (u32)(t+1));

            f32x4 acc0 = {0.f,0.f,0.f,0.f}, acc1 = {0.f,0.f,0.f,0.f};
            #pragma unroll
            for (int kt=0;kt<16;++kt){
                bf16x8 a0 = *(const bf16x8*)((char*)lds_a + swz(lane&15, kt*64 + (lane>>4)*16));
                bf16x8 a1 = *(const bf16x8*)((char*)lds_b + swz(lane&15, kt*64 + (lane>>4)*16));
                acc0 = MFMA(a0, bi0[kt], acc0);
                acc1 = MFMA(a0, bi1[kt], acc1);
                acc0 = MFMA(a1, bh0[kt], acc0);
                acc1 = MFMA(a1, bh1[kt], acc1);
            }
            {
                int gr=(lane>>4)*4, gc=lane&15;
                #pragma unroll
                for (int j=0;j<4;++j){
                    lds_g[(gr+j)*GCP_ + 2*w*16      + gc] = acc0[j];
                    lds_g[(gr+j)*GCP_ + (2*w+1)*16  + gc] = acc1[j];
                }
            }
            __syncthreads();   // S3

            {
                float2 gi = *(const float2*)&lds_g[prow*GCP_ +      phc];
                float2 gf = *(const float2*)&lds_g[prow*GCP_ + 32 + phc];
                float2 gg = *(const float2*)&lds_g[prow*GCP_ + 64 + phc];
                float2 go = *(const float2*)&lds_g[prow*GCP_ + 96 + phc];
                c0 = sigf(gf.x+bias[2])*c0 + sigf(gi.x+bias[0])*tanh_f(gg.x+bias[4]);
                c1 = sigf(gf.y+bias[3])*c1 + sigf(gi.y+bias[1])*tanh_f(gg.y+bias[5]);
                float h0v = sigf(go.x+bias[6])*tanh_f(c0);
                float h1v = sigf(go.y+bias[7])*tanh_f(c1);
                const u32 tg = (u32)(t+1)<<16;
                u32* dst = h1f + ((size_t)(t&(R_-1))*B_ + gb + prow)*H_ + n0 + phc;
                st_h2(dst, tg | (u32)f2b(h0v), tg | (u32)f2b(h1v), L2P);
                if (t == T_-1) {
                    hlast[(size_t)(gb+prow)*H_ + n0 + phc    ] = h0v;
                    hlast[(size_t)(gb+prow)*H_ + n0 + phc + 1] = h1v;
                }
            }
        }
    }
}

// ---------------- output head ----------------
__global__ void k_out(const float* __restrict__ hlast, const float* __restrict__ Wout,
                      const float* __restrict__ bout, float* __restrict__ y)
{
    int b = blockIdx.x;
    int w = threadIdx.x>>6, lane = threadIdx.x&63;
    const float* hp = hlast + (size_t)b*H_;
    #pragma unroll
    for (int oo=0; oo<4; ++oo) {
        int o = w*4 + oo;
        const float* wp = Wout + (size_t)o*H_;
        float p = 0.f;
        for (int k=lane; k<H_; k+=64) p += hp[k]*wp[k];
        #pragma unroll
        for (int off=32; off; off>>=1) p += __shfl_down(p, off);
        if (lane==0) y[b*16 + o] = p + bout[o];
    }
}

// ---------------- workspace layout (~8.6MB): [fast 2MB | mirror 2MB] x 2 rings ----------------
static constexpr size_t OFF_H0F = 0;
static constexpr size_t OFF_H1F = OFF_H0F + 2*MIRu*4;            // 4MB (fast+mirror)
static constexpr size_t OFF_HL  = OFF_H1F + 2*MIRu*4;            // 4MB
static constexpr size_t OFF_CTL = OFF_HL  + (size_t)B_*H_*4;     // 256KB

extern "C" void kernel_launch(void* const* d_in, const int* in_sizes, int n_in,
                              void* d_out, int out_size, void* d_ws, size_t ws_size,
                              hipStream_t stream)
{
    (void)in_sizes; (void)n_in; (void)out_size; (void)ws_size;
    const float* x    = (const float*)d_in[0];
    const float* cond = (const float*)d_in[1];
    const float* Wc   = (const float*)d_in[2];
    const float* bc   = (const float*)d_in[3];
    const float* Wi   = (const float*)d_in[4];
    const float* bi   = (const float*)d_in[5];
    const float* Wih0 = (const float*)d_in[6];
    const float* Whh0 = (const float*)d_in[7];
    const float* bih0 = (const float*)d_in[8];
    const float* bhh0 = (const float*)d_in[9];
    const float* Wih1 = (const float*)d_in[10];
    const float* Whh1 = (const float*)d_in[11];
    const float* bih1 = (const float*)d_in[12];
    const float* bhh1 = (const float*)d_in[13];
    const float* Wout = (const float*)d_in[14];
    const float* bout = (const float*)d_in[15];
    float* y = (float*)d_out;
    char* ws = (char*)d_ws;

    u32* h0f  = (u32*)(ws + OFF_H0F);
    u32* h1f  = (u32*)(ws + OFF_H1F);
    float* hl = (float*)(ws + OFF_HL);
    u32* ctl  = (u32*)(ws + OFF_CTL);

    k_prep<<<B_, 512, 0, stream>>>(cond, Wc, bc, Wi, bi, h0f, h1f, ctl);

    k_fused<<<2*NBH_*NG_, 256, 0, stream>>>(x, Wih0, Whh0, Wih1, Whh1,
                                            bih0, bhh0, bih1, bhh1,
                                            h0f, h1f, ctl, hl);

    k_out<<<B_, 256, 0, stream>>>(hl, Wout, bout, y);
}